// Round 5
// baseline (530.267 us; speedup 1.0000x reference)
//
#include <hip/hip_runtime.h>
#include <hip/hip_bf16.h>
#include <math.h>

#define EPS  1e-7f
#define MAXT 0.999999f   // 1 - 1e-6

typedef short  s16x8  __attribute__((ext_vector_type(8)));
typedef float  f32x16 __attribute__((ext_vector_type(16)));
typedef float  f32x4  __attribute__((ext_vector_type(4)));

__device__ __forceinline__ float waveRedSum(float v) {
    #pragma unroll
    for (int off = 32; off > 0; off >>= 1)
        v += __shfl_xor(v, off, 64);
    return v;
}

__device__ __forceinline__ unsigned short f2bf(float f) {
    unsigned u = __float_as_uint(f);
    u += 0x7fff + ((u >> 16) & 1);          // RNE, inputs are finite
    return (unsigned short)(u >> 16);
}

// ---------------------------------------------------------------------------
// Kernel A: v = log0( h_add( exp0( log0(x) @ embed ), embed_bias ) )
// v written as bf16 in MFMA-B packed layout: V[(k>>4)*2048 + n*16 + (k&15)]
// One wave per row; lane handles cols {2l, 2l+1}.
// ---------------------------------------------------------------------------
__global__ __launch_bounds__(256) void kA(const float* __restrict__ x,
                                          const float* __restrict__ embed,
                                          const float* __restrict__ ebias,
                                          unsigned short* __restrict__ vpack) {
    __shared__ float u[4][128];
    const int wave = threadIdx.x >> 6;
    const int lane = threadIdx.x & 63;
    const int row  = blockIdx.x * 4 + wave;
    const int c0   = lane * 2;

    const float2 xr = *(const float2*)(x + (size_t)row * 128 + c0);

    // log0(x)
    float n2 = waveRedSum(xr.x * xr.x + xr.y * xr.y);
    float n  = fmaxf(sqrtf(n2), EPS);
    float sc = atanhf(fminf(n, MAXT)) / n;
    u[wave][c0]     = xr.x * sc;
    u[wave][c0 + 1] = xr.y * sc;
    __syncthreads();

    // u @ embed
    float a0 = 0.f, a1 = 0.f;
    #pragma unroll 8
    for (int k = 0; k < 128; k++) {
        float  uk = u[wave][k];
        float2 e  = *(const float2*)(embed + (size_t)k * 128 + c0);
        a0 = fmaf(uk, e.x, a0);
        a1 = fmaf(uk, e.y, a1);
    }

    // exp0
    float np2 = waveRedSum(a0 * a0 + a1 * a1);
    float np  = fmaxf(sqrtf(np2), EPS);
    float se  = tanhf(np) / np;
    float h0 = a0 * se, h1 = a1 * se;
    float x2 = np2 * se * se;                    // |h|^2

    // h_add(h, embed_bias)
    float bx = ebias[c0], by = ebias[c0 + 1];
    float xy = waveRedSum(h0 * bx + h1 * by);
    float y2 = waveRedSum(bx * bx + by * by);
    float den = fmaxf(1.f + 2.f * xy + x2 * y2, EPS);
    float cx = 1.f + 2.f * xy + y2;
    float cy = 1.f - x2;
    float hb0 = (cx * h0 + cy * bx) / den;
    float hb1 = (cx * h1 + cy * by) / den;

    // log0(hb)
    float m2 = waveRedSum(hb0 * hb0 + hb1 * hb1);
    float m  = fmaxf(sqrtf(m2), EPS);
    float sl = atanhf(fminf(m, MAXT)) / m;
    float v0 = hb0 * sl, v1 = hb1 * sl;

    const int tbase = (row >> 4) * 2048 + (row & 15);
    vpack[tbase + c0 * 16]       = f2bf(v0);
    vpack[tbase + (c0 + 1) * 16] = f2bf(v1);
}

// ---------------------------------------------------------------------------
// Kernel B: t = adj @ v   (M=8192, N=128, K=8192), bf16 MFMA, fp32 partials.
// Barrier-free; wave owns 32 rows x 128 cols (4 acc tiles). The prior rounds
// all capped at ~1.8 TB/s because only ONE 2KB A-chunk was in flight per wave
// and B-frags were consumed the cycle after issue (Little's law:
// ~8KB/CU / ~2500cyc = 3 B/cyc). Fix: explicit software pipeline —
// 4-deep A register ring (8KB in flight/wave) + 2-deep B ring (covers L2
// latency). Unroll x4 makes ring indices compile-time -> stays in VGPRs.
// No barriers -> compiler emits fine-grained per-consumer vmcnt(N).
// HW v_cvt_pk_bf16_f32 for the A conversion (4 ops vs ~40).
// ---------------------------------------------------------------------------
__device__ __forceinline__ s16x8 pack_bf16x8(const f32x4 a, const f32x4 b) {
    union { __hip_bfloat162 h[4]; s16x8 v; } r;
    r.h[0] = __float22bfloat162_rn({a.x, a.y});
    r.h[1] = __float22bfloat162_rn({a.z, a.w});
    r.h[2] = __float22bfloat162_rn({b.x, b.y});
    r.h[3] = __float22bfloat162_rn({b.z, b.w});
    return r.v;
}

__global__ __launch_bounds__(256) void kB(const float* __restrict__ adj,
                                          const unsigned short* __restrict__ vpack,
                                          float* __restrict__ tpart,
                                          int klen) {
    const int wave = threadIdx.x >> 6;
    const int lane = threadIdx.x & 63;
    const int rt   = blockIdx.x * 4 + wave;     // row-tile 0..255
    const int r0   = rt * 32;
    const int k0   = blockIdx.y * klen;
    float* tout    = tpart + (size_t)blockIdx.y * (8192 * 128);

    const int m  = lane & 31;                   // A row / C col within tile
    const int kh = lane >> 5;                   // k-half: k = kh*8 + j

    // A: row r0+m, 8 fp32 at column (k0 + c*16 + kh*8); lanes m,m+32 cover
    // one full 64B line per chunk -> dense request pattern.
    const float* abase = adj + (size_t)(r0 + m) * 8192 + k0 + kh * 8;
    // B: packed layout base for this lane
    const unsigned short* bbase = vpack + (size_t)(k0 >> 4) * 2048 + m * 16 + kh * 8;

    const int kiters = klen >> 4;               // 16-float chunks, multiple of 4

    f32x16 acc0 = {0.f}, acc1 = {0.f}, acc2 = {0.f}, acc3 = {0.f};

    f32x4 aq[4][2];     // 4-chunk A prefetch ring
    s16x8 bq[2][4];     // 2-chunk B prefetch ring

    #pragma unroll
    for (int c = 0; c < 4; ++c) {
        aq[c][0] = *(const f32x4*)(abase + c * 16);
        aq[c][1] = *(const f32x4*)(abase + c * 16 + 4);
    }
    #pragma unroll
    for (int c = 0; c < 2; ++c) {
        const unsigned short* bp = bbase + (size_t)c * 2048;
        bq[c][0] = *(const s16x8*)(bp);
        bq[c][1] = *(const s16x8*)(bp + 512);
        bq[c][2] = *(const s16x8*)(bp + 1024);
        bq[c][3] = *(const s16x8*)(bp + 1536);
    }

    for (int it = 0; it < kiters; it += 4) {
        #pragma unroll
        for (int u = 0; u < 4; ++u) {
            const int c = it + u;               // chunk index; c&3==u, c&1==u&1
            s16x8 af = pack_bf16x8(aq[u][0], aq[u][1]);
            acc0 = __builtin_amdgcn_mfma_f32_32x32x16_bf16(af, bq[u & 1][0], acc0, 0, 0, 0);
            acc1 = __builtin_amdgcn_mfma_f32_32x32x16_bf16(af, bq[u & 1][1], acc1, 0, 0, 0);
            acc2 = __builtin_amdgcn_mfma_f32_32x32x16_bf16(af, bq[u & 1][2], acc2, 0, 0, 0);
            acc3 = __builtin_amdgcn_mfma_f32_32x32x16_bf16(af, bq[u & 1][3], acc3, 0, 0, 0);

            // refill B(c+2) into the slot just consumed (WAR handled by HW/compiler)
            {
                const int cb = min(c + 2, kiters - 1);
                const unsigned short* bp = bbase + (size_t)cb * 2048;
                bq[u & 1][0] = *(const s16x8*)(bp);
                bq[u & 1][1] = *(const s16x8*)(bp + 512);
                bq[u & 1][2] = *(const s16x8*)(bp + 1024);
                bq[u & 1][3] = *(const s16x8*)(bp + 1536);
            }
            // refill A(c+4) into ring slot u
            {
                const int ca = min(c + 4, kiters - 1);
                aq[u][0] = *(const f32x4*)(abase + (size_t)ca * 16);
                aq[u][1] = *(const f32x4*)(abase + (size_t)ca * 16 + 4);
            }
        }
    }

    // epilogue: C/D layout col=lane&31, row=(r&3)+8*(r>>2)+4*(lane>>5)
    #pragma unroll
    for (int r = 0; r < 16; ++r) {
        int row  = r0 + (r & 3) + 8 * (r >> 2) + 4 * kh;
        float* o = tout + (size_t)row * 128 + m;
        o[0]  = acc0[r];
        o[32] = acc1[r];
        o[64] = acc2[r];
        o[96] = acc3[r];
    }
}

// ---------------------------------------------------------------------------
// Kernel C: out = h_add( exp0( log0([x ; exp0(t)]) @ layer ), layer_bias )
// Sums the S partial slices of t, then one wave per row; lane = cols {2l,2l+1}.
// ---------------------------------------------------------------------------
__global__ __launch_bounds__(256) void kC(const float* __restrict__ x,
                                          const float* __restrict__ tpart,
                                          const float* __restrict__ layer,
                                          const float* __restrict__ lbias,
                                          float* __restrict__ out,
                                          int S) {
    __shared__ float w[4][256];
    const int wave = threadIdx.x >> 6;
    const int lane = threadIdx.x & 63;
    const int row  = blockIdx.x * 4 + wave;
    const int c0   = lane * 2;

    float2 tr = *(const float2*)(tpart + (size_t)row * 128 + c0);
    for (int s = 1; s < S; s++) {
        float2 p = *(const float2*)(tpart + (size_t)s * 8192 * 128 + (size_t)row * 128 + c0);
        tr.x += p.x; tr.y += p.y;
    }
    const float2 xr = *(const float2*)(x + (size_t)row * 128 + c0);

    float st = waveRedSum(tr.x * tr.x + tr.y * tr.y);   // |t|^2
    float sx = waveRedSum(xr.x * xr.x + xr.y * xr.y);   // |x|^2

    // neigh = exp0(t) = t * se
    float nt = fmaxf(sqrtf(st), EPS);
    float se = tanhf(nt) / nt;

    // w = log0([x ; neigh])  (norm over the 256-dim concat)
    float ncat2 = sx + st * se * se;
    float ncat  = fmaxf(sqrtf(ncat2), EPS);
    float sw    = atanhf(fminf(ncat, MAXT)) / ncat;
    w[wave][c0]           = xr.x * sw;
    w[wave][c0 + 1]       = xr.y * sw;
    w[wave][128 + c0]     = tr.x * se * sw;
    w[wave][128 + c0 + 1] = tr.y * se * sw;
    __syncthreads();

    // w @ layer
    float a0 = 0.f, a1 = 0.f;
    #pragma unroll 8
    for (int k = 0; k < 256; k++) {
        float  wk = w[wave][k];
        float2 e  = *(const float2*)(layer + (size_t)k * 128 + c0);
        a0 = fmaf(wk, e.x, a0);
        a1 = fmaf(wk, e.y, a1);
    }

    // exp0
    float np2 = waveRedSum(a0 * a0 + a1 * a1);
    float np  = fmaxf(sqrtf(np2), EPS);
    float so  = tanhf(np) / np;
    float o0 = a0 * so, o1 = a1 * so;
    float x2 = np2 * so * so;

    // h_add(o, layer_bias)
    float bx = lbias[c0], by = lbias[c0 + 1];
    float xy = waveRedSum(o0 * bx + o1 * by);
    float y2 = waveRedSum(bx * bx + by * by);
    float den = fmaxf(1.f + 2.f * xy + x2 * y2, EPS);
    float cx = 1.f + 2.f * xy + y2;
    float cy = 1.f - x2;

    float2 res;
    res.x = (cx * o0 + cy * bx) / den;
    res.y = (cx * o1 + cy * by) / den;
    *(float2*)(out + (size_t)row * 128 + c0) = res;
}

// ---------------------------------------------------------------------------
extern "C" void kernel_launch(void* const* d_in, const int* in_sizes, int n_in,
                              void* d_out, int out_size, void* d_ws, size_t ws_size,
                              hipStream_t stream) {
    const float* x     = (const float*)d_in[0];   // [8192,128]
    const float* adj   = (const float*)d_in[1];   // [8192,8192]
    const float* embed = (const float*)d_in[2];   // [128,128]
    const float* layer = (const float*)d_in[3];   // [256,128]
    const float* eb    = (const float*)d_in[4];   // [128]
    const float* lb    = (const float*)d_in[5];   // [128]
    float* out = (float*)d_out;

    const size_t vbytes = (size_t)8192 * 128 * 2;          // 2 MB bf16 packed
    const size_t slice  = (size_t)8192 * 128 * 4;          // 4 MB fp32 partial

    int S = 1;
    if      (ws_size >= vbytes + 8 * slice) S = 8;
    else if (ws_size >= vbytes + 4 * slice) S = 4;
    else if (ws_size >= vbytes + 2 * slice) S = 2;

    unsigned short* vpack = (unsigned short*)d_ws;
    float* tpart = (float*)((char*)d_ws + vbytes);

    kA<<<2048, 256, 0, stream>>>(x, embed, eb, vpack);
    kB<<<dim3(64, S), 256, 0, stream>>>(adj, vpack, tpart, 8192 / S);
    kC<<<2048, 256, 0, stream>>>(x, tpart, layer, lb, out, S);
}

// Round 7
// 506.205 us; speedup vs baseline: 1.0475x; 1.0475x over previous
//
#include <hip/hip_runtime.h>
#include <hip/hip_bf16.h>
#include <math.h>

#define EPS  1e-7f
#define MAXT 0.999999f   // 1 - 1e-6

typedef short  s16x8  __attribute__((ext_vector_type(8)));
typedef float  f32x16 __attribute__((ext_vector_type(16)));
typedef float  f32x4  __attribute__((ext_vector_type(4)));

__device__ __forceinline__ float waveRedSum(float v) {
    #pragma unroll
    for (int off = 32; off > 0; off >>= 1)
        v += __shfl_xor(v, off, 64);
    return v;
}

__device__ __forceinline__ unsigned short f2bf(float f) {
    unsigned u = __float_as_uint(f);
    u += 0x7fff + ((u >> 16) & 1);          // RNE, inputs are finite
    return (unsigned short)(u >> 16);
}

// ---------------------------------------------------------------------------
// Kernel A: v = log0( h_add( exp0( log0(x) @ embed ), embed_bias ) )
// v written as bf16 in MFMA-B packed layout: V[(k>>4)*2048 + n*16 + (k&15)]
// One wave per row; lane handles cols {2l, 2l+1}.
// ---------------------------------------------------------------------------
__global__ __launch_bounds__(256) void kA(const float* __restrict__ x,
                                          const float* __restrict__ embed,
                                          const float* __restrict__ ebias,
                                          unsigned short* __restrict__ vpack) {
    __shared__ float u[4][128];
    const int wave = threadIdx.x >> 6;
    const int lane = threadIdx.x & 63;
    const int row  = blockIdx.x * 4 + wave;
    const int c0   = lane * 2;

    const float2 xr = *(const float2*)(x + (size_t)row * 128 + c0);

    // log0(x)
    float n2 = waveRedSum(xr.x * xr.x + xr.y * xr.y);
    float n  = fmaxf(sqrtf(n2), EPS);
    float sc = atanhf(fminf(n, MAXT)) / n;
    u[wave][c0]     = xr.x * sc;
    u[wave][c0 + 1] = xr.y * sc;
    __syncthreads();

    // u @ embed
    float a0 = 0.f, a1 = 0.f;
    #pragma unroll 8
    for (int k = 0; k < 128; k++) {
        float  uk = u[wave][k];
        float2 e  = *(const float2*)(embed + (size_t)k * 128 + c0);
        a0 = fmaf(uk, e.x, a0);
        a1 = fmaf(uk, e.y, a1);
    }

    // exp0
    float np2 = waveRedSum(a0 * a0 + a1 * a1);
    float np  = fmaxf(sqrtf(np2), EPS);
    float se  = tanhf(np) / np;
    float h0 = a0 * se, h1 = a1 * se;
    float x2 = np2 * se * se;                    // |h|^2

    // h_add(h, embed_bias)
    float bx = ebias[c0], by = ebias[c0 + 1];
    float xy = waveRedSum(h0 * bx + h1 * by);
    float y2 = waveRedSum(bx * bx + by * by);
    float den = fmaxf(1.f + 2.f * xy + x2 * y2, EPS);
    float cx = 1.f + 2.f * xy + y2;
    float cy = 1.f - x2;
    float hb0 = (cx * h0 + cy * bx) / den;
    float hb1 = (cx * h1 + cy * by) / den;

    // log0(hb)
    float m2 = waveRedSum(hb0 * hb0 + hb1 * hb1);
    float m  = fmaxf(sqrtf(m2), EPS);
    float sl = atanhf(fminf(m, MAXT)) / m;
    float v0 = hb0 * sl, v1 = hb1 * sl;

    const int tbase = (row >> 4) * 2048 + (row & 15);
    vpack[tbase + c0 * 16]       = f2bf(v0);
    vpack[tbase + (c0 + 1) * 16] = f2bf(v1);
}

// ---------------------------------------------------------------------------
// Kernel B: t = adj @ v   (M=8192, N=128, K=8192), bf16 MFMA, fp32 partials.
// Zero barriers. Wave owns 32 rows x 128 cols (4 acc tiles, 64 AGPR).
// Per superchunk (32 rows x 128 cols fp32 = 16 KB):
//   1) one burst of 16 global_load_dwordx4, each covering 2 full rows x 512B
//      contiguous -> 16 fully-dense 64B lines per instruction (prefetched one
//      superchunk ahead; the single vmcnt wait is covered by compute and by
//      the other independent waves on the CU);
//   2) v_cvt_pk_bf16_f32 + ds_write_b64 into a WAVE-PRIVATE LDS fragment
//      buffer (packed [kc][m][k%16], kc-block padded to 1040B) — same-wave DS
//      ordering makes this safe with no __syncthreads anywhere;
//   3) 8 k-chunks: ds_read_b128 A-frag + 4 MFMAs; B frags from L2-resident
//      vpack via a 2-deep register ring.
// ROUND-6 BUG FIX: grid was dim3(16,S) -> only 64 of 256 row-tiles computed
// (rows 2048+ read poisoned tpart). Correct grid: dim3(64,S).
// ---------------------------------------------------------------------------
#define KCPAD 1040   // bytes per kc-block in LDS (1024 + 16 pad)

__global__ __launch_bounds__(256) void kB(const float* __restrict__ adj,
                                          const unsigned short* __restrict__ vpack,
                                          float* __restrict__ tpart,
                                          int klen) {
    __shared__ __align__(16) unsigned char lds[4][8 * KCPAD];

    const int wave = threadIdx.x >> 6;
    const int lane = threadIdx.x & 63;
    const int rt   = blockIdx.x * 4 + wave;     // row-tile 0..255
    const int r0   = rt * 32;
    const int k0   = blockIdx.y * klen;
    float* tout    = tpart + (size_t)blockIdx.y * (8192 * 128);

    const int m  = lane & 31;                   // A row / C col within tile
    const int kh = lane >> 5;                   // k-half: k = kh*8 + j
    unsigned char* buf = lds[wave];

    // --- A staging addressing: instr j covers rows {2j, 2j+1} of the tile.
    // lane<32 -> row 2j, lane>=32 -> row 2j+1; cols 4*(lane&31) .. +3.
    const int lr = lane >> 5;                   // row parity within pair
    const int c0 = (lane & 31) * 4;             // col within superchunk
    const float* aload = adj + (size_t)(r0 + lr) * 8192 + k0 + c0;
    // per-lane LDS write base: kc = c0>>4, ofs = (c0&15)*2, + j*64 per instr
    unsigned char* wbase = buf + (c0 >> 4) * KCPAD + lr * 32 + (c0 & 15) * 2;

    // --- B addressing (packed layout; g = global 16-col chunk index)
    const int g0 = k0 >> 4;
    const int glast = (klen >> 4) - 1;
    const unsigned short* bb = vpack + (size_t)m * 16 + kh * 8;

    f32x16 acc0 = {0.f}, acc1 = {0.f}, acc2 = {0.f}, acc3 = {0.f};

    // prologue: superchunk 0 A burst
    f32x4 ar[16];
    #pragma unroll
    for (int j = 0; j < 16; ++j)
        ar[j] = *(const f32x4*)(aload + (size_t)(2 * j) * 8192);

    // prologue: B ring g=0,1
    s16x8 bq[2][4];
    #pragma unroll
    for (int c = 0; c < 2; ++c) {
        const unsigned short* bp = bb + (size_t)(g0 + c) * 2048;
        bq[c][0] = *(const s16x8*)(bp);
        bq[c][1] = *(const s16x8*)(bp + 512);
        bq[c][2] = *(const s16x8*)(bp + 1024);
        bq[c][3] = *(const s16x8*)(bp + 1536);
    }

    const int nsc = klen >> 7;                  // superchunks (klen/128)
    for (int sc = 0; sc < nsc; ++sc) {
        // 1) pack current A regs -> wave-private LDS (ds_write_b64 x16)
        #pragma unroll
        for (int j = 0; j < 16; ++j) {
            union { __hip_bfloat162 h[2]; uint2 w; } p;
            p.h[0] = __float22bfloat162_rn({ar[j].x, ar[j].y});
            p.h[1] = __float22bfloat162_rn({ar[j].z, ar[j].w});
            *(uint2*)(wbase + j * 64) = p.w;
        }

        // 2) burst-issue next superchunk's 16 A loads (1 superchunk lookahead)
        if (sc + 1 < nsc) {
            aload += 128;
            #pragma unroll
            for (int j = 0; j < 16; ++j)
                ar[j] = *(const f32x4*)(aload + (size_t)(2 * j) * 8192);
        }

        // 3) compute 8 k-chunks from LDS; B ring refill at distance 2
        #pragma unroll
        for (int kc = 0; kc < 8; ++kc) {
            const int g    = sc * 8 + kc;
            const int slot = g & 1;
            s16x8 a = *(const s16x8*)(buf + kc * KCPAD + m * 32 + kh * 16);
            acc0 = __builtin_amdgcn_mfma_f32_32x32x16_bf16(a, bq[slot][0], acc0, 0, 0, 0);
            acc1 = __builtin_amdgcn_mfma_f32_32x32x16_bf16(a, bq[slot][1], acc1, 0, 0, 0);
            acc2 = __builtin_amdgcn_mfma_f32_32x32x16_bf16(a, bq[slot][2], acc2, 0, 0, 0);
            acc3 = __builtin_amdgcn_mfma_f32_32x32x16_bf16(a, bq[slot][3], acc3, 0, 0, 0);
            int gn = g + 2; if (gn > glast) gn = glast;
            const unsigned short* bp = bb + (size_t)(g0 + gn) * 2048;
            bq[slot][0] = *(const s16x8*)(bp);
            bq[slot][1] = *(const s16x8*)(bp + 512);
            bq[slot][2] = *(const s16x8*)(bp + 1024);
            bq[slot][3] = *(const s16x8*)(bp + 1536);
        }
    }

    // epilogue: C/D layout col=lane&31, row=(r&3)+8*(r>>2)+4*(lane>>5)
    #pragma unroll
    for (int r = 0; r < 16; ++r) {
        int row  = r0 + (r & 3) + 8 * (r >> 2) + 4 * kh;
        float* o = tout + (size_t)row * 128 + m;
        o[0]  = acc0[r];
        o[32] = acc1[r];
        o[64] = acc2[r];
        o[96] = acc3[r];
    }
}

// ---------------------------------------------------------------------------
// Kernel C: out = h_add( exp0( log0([x ; exp0(t)]) @ layer ), layer_bias )
// Sums the S partial slices of t, then one wave per row; lane = cols {2l,2l+1}.
// ---------------------------------------------------------------------------
__global__ __launch_bounds__(256) void kC(const float* __restrict__ x,
                                          const float* __restrict__ tpart,
                                          const float* __restrict__ layer,
                                          const float* __restrict__ lbias,
                                          float* __restrict__ out,
                                          int S) {
    __shared__ float w[4][256];
    const int wave = threadIdx.x >> 6;
    const int lane = threadIdx.x & 63;
    const int row  = blockIdx.x * 4 + wave;
    const int c0   = lane * 2;

    float2 tr = *(const float2*)(tpart + (size_t)row * 128 + c0);
    for (int s = 1; s < S; s++) {
        float2 p = *(const float2*)(tpart + (size_t)s * 8192 * 128 + (size_t)row * 128 + c0);
        tr.x += p.x; tr.y += p.y;
    }
    const float2 xr = *(const float2*)(x + (size_t)row * 128 + c0);

    float st = waveRedSum(tr.x * tr.x + tr.y * tr.y);   // |t|^2
    float sx = waveRedSum(xr.x * xr.x + xr.y * xr.y);   // |x|^2

    // neigh = exp0(t) = t * se
    float nt = fmaxf(sqrtf(st), EPS);
    float se = tanhf(nt) / nt;

    // w = log0([x ; neigh])  (norm over the 256-dim concat)
    float ncat2 = sx + st * se * se;
    float ncat  = fmaxf(sqrtf(ncat2), EPS);
    float sw    = atanhf(fminf(ncat, MAXT)) / ncat;
    w[wave][c0]           = xr.x * sw;
    w[wave][c0 + 1]       = xr.y * sw;
    w[wave][128 + c0]     = tr.x * se * sw;
    w[wave][128 + c0 + 1] = tr.y * se * sw;
    __syncthreads();

    // w @ layer
    float a0 = 0.f, a1 = 0.f;
    #pragma unroll 8
    for (int k = 0; k < 256; k++) {
        float  wk = w[wave][k];
        float2 e  = *(const float2*)(layer + (size_t)k * 128 + c0);
        a0 = fmaf(wk, e.x, a0);
        a1 = fmaf(wk, e.y, a1);
    }

    // exp0
    float np2 = waveRedSum(a0 * a0 + a1 * a1);
    float np  = fmaxf(sqrtf(np2), EPS);
    float so  = tanhf(np) / np;
    float o0 = a0 * so, o1 = a1 * so;
    float x2 = np2 * so * so;

    // h_add(o, layer_bias)
    float bx = lbias[c0], by = lbias[c0 + 1];
    float xy = waveRedSum(o0 * bx + o1 * by);
    float y2 = waveRedSum(bx * bx + by * by);
    float den = fmaxf(1.f + 2.f * xy + x2 * y2, EPS);
    float cx = 1.f + 2.f * xy + y2;
    float cy = 1.f - x2;

    float2 res;
    res.x = (cx * o0 + cy * bx) / den;
    res.y = (cx * o1 + cy * by) / den;
    *(float2*)(out + (size_t)row * 128 + c0) = res;
}

// ---------------------------------------------------------------------------
extern "C" void kernel_launch(void* const* d_in, const int* in_sizes, int n_in,
                              void* d_out, int out_size, void* d_ws, size_t ws_size,
                              hipStream_t stream) {
    const float* x     = (const float*)d_in[0];   // [8192,128]
    const float* adj   = (const float*)d_in[1];   // [8192,8192]
    const float* embed = (const float*)d_in[2];   // [128,128]
    const float* layer = (const float*)d_in[3];   // [256,128]
    const float* eb    = (const float*)d_in[4];   // [128]
    const float* lb    = (const float*)d_in[5];   // [128]
    float* out = (float*)d_out;

    const size_t vbytes = (size_t)8192 * 128 * 2;          // 2 MB bf16 packed
    const size_t slice  = (size_t)8192 * 128 * 4;          // 4 MB fp32 partial

    int S = 1;
    if      (ws_size >= vbytes + 8 * slice) S = 8;
    else if (ws_size >= vbytes + 4 * slice) S = 4;
    else if (ws_size >= vbytes + 2 * slice) S = 2;

    unsigned short* vpack = (unsigned short*)d_ws;
    float* tpart = (float*)((char*)d_ws + vbytes);

    kA<<<2048, 256, 0, stream>>>(x, embed, eb, vpack);
    kB<<<dim3(64, S), 256, 0, stream>>>(adj, vpack, tpart, 8192 / S);
    kC<<<2048, 256, 0, stream>>>(x, tpart, layer, lb, out, S);
}